// Round 1
// baseline (707.696 us; speedup 1.0000x reference)
//
#include <hip/hip_runtime.h>
#include <math.h>

#define B 32
#define N 16384
#define M 128
#define D 1024
#define L 390   // 3*M+6
#define EPSF 1e-16f

// ws layout (floats):
//   [O_OFF,  O_OFF+B*L)   o = emb@W + b   (k = o[:,0:128], e-logits, a live here)
//   [P_OFF,  P_OFF+B*8)   per-batch params {beta,g,s0,s1,s2,gamma,knorm,pad}
//   [S1_OFF, +B)          sum exp(z)   (atomic)
//   [S2_OFF, +B)          sum w_sh     (atomic)
//   [Z_OFF,  +B*N)        z = beta*sim
#define O_OFF  0
#define P_OFF  (B*L)
#define S1_OFF (P_OFF + B*8)
#define S2_OFF (S1_OFF + B)
#define Z_OFF  (S2_OFF + B)

__device__ __forceinline__ float softplusf(float x) {
    return x > 20.f ? x : log1pf(expf(x));
}
__device__ __forceinline__ float sigmoidf(float x) {
    return 1.f / (1.f + expf(-x));
}

// K1: o[b, l0:l0+64] = emb[b,:] @ W[:, l0:l0+64] + bias.  grid(7, B), 256 thr.
__global__ __launch_bounds__(256) void k1_gemm(const float* __restrict__ emb,
                                               const float* __restrict__ W,
                                               const float* __restrict__ bias,
                                               float* __restrict__ ws) {
    __shared__ float embS[D];
    __shared__ float red[4][64];
    const int l0 = blockIdx.x * 64;
    const int b  = blockIdx.y;
    const int t  = threadIdx.x;
    for (int i = t; i < D; i += 256) embS[i] = emb[b * D + i];
    __syncthreads();
    const int li = t & 63;
    const int q  = t >> 6;          // 4-way split of the D dimension
    const int l  = l0 + li;
    float partial = 0.f;
    if (l < L) {
        const float* wp = W + (size_t)(q * 256) * L + l;
        #pragma unroll 4
        for (int d = 0; d < 256; ++d) partial += embS[q * 256 + d] * wp[(size_t)d * L];
    }
    red[q][li] = partial;
    __syncthreads();
    if (t < 64 && l0 + t < L) {
        float o = red[0][t] + red[1][t] + red[2][t] + red[3][t] + bias[l0 + t];
        ws[O_OFF + b * L + l0 + t] = o;
    }
}

// K1b: per-batch scalar params + zero atomics. grid(B), 128 thr.
__global__ __launch_bounds__(128) void k1b_act(float* __restrict__ ws) {
    const int b = blockIdx.x;
    const int t = threadIdx.x;                 // 128 threads = 2 waves
    const float* o = ws + O_OFF + b * L;
    float kv = o[t];
    float sq = kv * kv;
    #pragma unroll
    for (int off = 32; off >= 1; off >>= 1) sq += __shfl_xor(sq, off, 64);
    __shared__ float s01[2];
    if ((t & 63) == 0) s01[t >> 6] = sq;
    __syncthreads();
    if (t == 0) {
        float knorm = sqrtf(s01[0] + s01[1]);
        float beta  = softplusf(o[M]);
        float g     = sigmoidf(o[M + 1]);
        float x0 = o[M + 2], x1 = o[M + 3], x2 = o[M + 4];
        float mx = fmaxf(x0, fmaxf(x1, x2));
        float e0 = expf(x0 - mx), e1 = expf(x1 - mx), e2 = expf(x2 - mx);
        float inv = 1.f / (e0 + e1 + e2);
        float gamma = 1.f + softplusf(o[M + 5]);
        float* p = ws + P_OFF + b * 8;
        p[0] = beta; p[1] = g; p[2] = e0 * inv; p[3] = e1 * inv; p[4] = e2 * inv;
        p[5] = gamma; p[6] = knorm;
        ws[S1_OFF + b] = 0.f;
        ws[S2_OFF + b] = 0.f;
    }
}

// K2: z[b,n] = beta * cos_sim(mem[b,n,:], k[b,:]); atomic S1 += sum exp(z).
// grid(N/64, B), 256 thr = 4 waves, one wave per row, 16 rows/wave.
__global__ __launch_bounds__(256) void k2_sim(const float* __restrict__ mem,
                                              float* __restrict__ ws) {
    const int b    = blockIdx.y;
    const int n0   = blockIdx.x * 64;
    const int t    = threadIdx.x;
    const int wave = t >> 6, lane = t & 63;
    __shared__ float kS[M];
    if (t < M) kS[t] = ws[O_OFF + b * L + t];
    __syncthreads();
    const float beta  = ws[P_OFF + b * 8 + 0];
    const float knorm = ws[P_OFF + b * 8 + 6];
    float* z = ws + Z_OFF + (size_t)b * N;
    const float k0 = kS[2 * lane], k1 = kS[2 * lane + 1];
    float lsum = 0.f;
    for (int i = 0; i < 16; ++i) {
        const int n = n0 + wave * 16 + i;
        const float2 mv = *(const float2*)(mem + ((size_t)b * N + n) * M + 2 * lane);
        float dot = mv.x * k0 + mv.y * k1;
        float sq  = mv.x * mv.x + mv.y * mv.y;
        #pragma unroll
        for (int off = 32; off >= 1; off >>= 1) {
            dot += __shfl_xor(dot, off, 64);
            sq  += __shfl_xor(sq,  off, 64);
        }
        const float sim = dot / (sqrtf(sq) * knorm + EPSF);
        const float zz  = beta * sim;
        if (lane == 0) { z[n] = zz; lsum += expf(zz); }
    }
    __shared__ float acc[4];
    if (lane == 0) acc[wave] = lsum;
    __syncthreads();
    if (t == 0) atomicAdd(ws + S1_OFF + b, acc[0] + acc[1] + acc[2] + acc[3]);
}

// K3: S2[b] = sum_n (s0*wg(n-1)+s1*wg(n)+s2*wg(n+1))^gamma.  grid(N/256, B).
__global__ __launch_bounds__(256) void k3_shsum(const float* __restrict__ w_prev,
                                                float* __restrict__ ws) {
    const int b = blockIdx.y;
    const int n = blockIdx.x * 256 + threadIdx.x;
    const float* p = ws + P_OFF + b * 8;
    const float g = p[1], s0 = p[2], s1 = p[3], s2 = p[4], gamma = p[5];
    const float invS1 = 1.f / ws[S1_OFF + b];
    const float* z  = ws + Z_OFF + (size_t)b * N;
    const float* wp = w_prev + (size_t)b * N;
    const int nm = (n == 0)     ? N - 1 : n - 1;
    const int np = (n == N - 1) ? 0     : n + 1;
    const float gm1 = 1.f - g;
    const float wgm = g * expf(z[nm]) * invS1 + gm1 * wp[nm];
    const float wg0 = g * expf(z[n ]) * invS1 + gm1 * wp[n ];
    const float wgp = g * expf(z[np]) * invS1 + gm1 * wp[np];
    const float wt  = s0 * wgm + s1 * wg0 + s2 * wgp;
    float v = powf(wt, gamma);
    #pragma unroll
    for (int off = 32; off >= 1; off >>= 1) v += __shfl_xor(v, off, 64);
    __shared__ float acc[4];
    if ((threadIdx.x & 63) == 0) acc[threadIdx.x >> 6] = v;
    __syncthreads();
    if (threadIdx.x == 0) atomicAdd(ws + S2_OFF + b, acc[0] + acc[1] + acc[2] + acc[3]);
}

// K4: w[b,n] = w_sh/(S2+eps); new_mem = mem*(1-w*e) + w*a.
// grid(N/64, B), 256 thr = 4 waves, one wave per row (recomputes w per row,
// wave-uniform so the 3 expf + powf cost one SIMT issue per row).
__global__ __launch_bounds__(256) void k4_write(const float* __restrict__ mem,
                                                const float* __restrict__ w_prev,
                                                const float* __restrict__ ws,
                                                float* __restrict__ out) {
    const int b    = blockIdx.y;
    const int n0   = blockIdx.x * 64;
    const int t    = threadIdx.x;
    const int wave = t >> 6, lane = t & 63;
    __shared__ float eS[M], aS[M];
    if (t < M) {
        eS[t] = sigmoidf(ws[O_OFF + b * L + M + 6 + t]);
        aS[t] = ws[O_OFF + b * L + 2 * M + 6 + t];
    }
    __syncthreads();
    const float* p = ws + P_OFF + b * 8;
    const float g = p[1], s0 = p[2], s1 = p[3], s2 = p[4], gamma = p[5];
    const float invS1 = 1.f / ws[S1_OFF + b];
    const float invS2 = 1.f / (ws[S2_OFF + b] + EPSF);
    const float* z  = ws + Z_OFF + (size_t)b * N;
    const float* wp = w_prev + (size_t)b * N;
    float* w_out = out + (size_t)b * N;
    float* m_out = out + (size_t)B * N;
    const float e0 = eS[2 * lane], e1 = eS[2 * lane + 1];
    const float a0 = aS[2 * lane], a1 = aS[2 * lane + 1];
    const float gm1 = 1.f - g;
    for (int i = 0; i < 16; ++i) {
        const int n  = n0 + wave * 16 + i;
        const int nm = (n == 0)     ? N - 1 : n - 1;
        const int np = (n == N - 1) ? 0     : n + 1;
        const float wgm = g * expf(z[nm]) * invS1 + gm1 * wp[nm];
        const float wg0 = g * expf(z[n ]) * invS1 + gm1 * wp[n ];
        const float wgp = g * expf(z[np]) * invS1 + gm1 * wp[np];
        const float wt  = s0 * wgm + s1 * wg0 + s2 * wgp;
        const float wv  = powf(wt, gamma) * invS2;
        if (lane == 0) w_out[n] = wv;
        const size_t idx = ((size_t)b * N + n) * M + 2 * lane;
        const float2 mv = *(const float2*)(mem + idx);
        float2 r;
        r.x = fmaf(mv.x, 1.f - wv * e0, wv * a0);
        r.y = fmaf(mv.y, 1.f - wv * e1, wv * a1);
        *(float2*)(m_out + idx) = r;
    }
}

extern "C" void kernel_launch(void* const* d_in, const int* in_sizes, int n_in,
                              void* d_out, int out_size, void* d_ws, size_t ws_size,
                              hipStream_t stream) {
    const float* emb    = (const float*)d_in[0];
    const float* w_prev = (const float*)d_in[1];
    const float* mem    = (const float*)d_in[2];
    const float* W      = (const float*)d_in[3];
    const float* bias   = (const float*)d_in[4];
    float* ws  = (float*)d_ws;    // needs (B*L + B*8 + 2*B + B*N)*4 ≈ 2.15 MB
    float* out = (float*)d_out;

    k1_gemm <<<dim3(7, B),      256, 0, stream>>>(emb, W, bias, ws);
    k1b_act <<<dim3(B),         128, 0, stream>>>(ws);
    k2_sim  <<<dim3(N / 64, B), 256, 0, stream>>>(mem, ws);
    k3_shsum<<<dim3(N / 256, B),256, 0, stream>>>(w_prev, ws);
    k4_write<<<dim3(N / 64, B), 256, 0, stream>>>(mem, w_prev, ws, out);
}

// Round 2
// 580.505 us; speedup vs baseline: 1.2191x; 1.2191x over previous
//
#include <hip/hip_runtime.h>
#include <math.h>

#define B 32
#define N 16384
#define M 128
#define D 1024
#define L 390   // 3*M+6
#define EPSF 1e-16f

// ws layout (floats):
//   [O_OFF,  O_OFF+B*L)   o = emb@W + b
//   [P_OFF,  P_OFF+B*8)   per-batch params {beta,g,s0,s1,s2,gamma,knorm,pad}
//   [S1_OFF, +B)          sum exp(z)   (atomic)
//   [S2_OFF, +B)          sum w_sh     (atomic)
//   [Z_OFF,  +B*N)        z = beta*sim
// w_sh itself is stashed in d_out's w region (k3 writes, k4 scales in place).
#define O_OFF  0
#define P_OFF  (B*L)
#define S1_OFF (P_OFF + B*8)
#define S2_OFF (S1_OFF + B)
#define Z_OFF  (S2_OFF + B)

__device__ __forceinline__ float softplusf(float x) {
    return x > 20.f ? x : log1pf(expf(x));
}
__device__ __forceinline__ float sigmoidf(float x) {
    return 1.f / (1.f + expf(-x));
}

// K1: o[b, l0:l0+64] = emb[b,:] @ W[:, l0:l0+64] + bias.  grid(7, B), 256 thr.
__global__ __launch_bounds__(256) void k1_gemm(const float* __restrict__ emb,
                                               const float* __restrict__ W,
                                               const float* __restrict__ bias,
                                               float* __restrict__ ws) {
    __shared__ float embS[D];
    __shared__ float red[4][64];
    const int l0 = blockIdx.x * 64;
    const int b  = blockIdx.y;
    const int t  = threadIdx.x;
    for (int i = t; i < D; i += 256) embS[i] = emb[b * D + i];
    __syncthreads();
    const int li = t & 63;
    const int q  = t >> 6;          // 4-way split of the D dimension
    const int l  = l0 + li;
    float partial = 0.f;
    if (l < L) {
        const float* wp = W + (size_t)(q * 256) * L + l;
        #pragma unroll 4
        for (int d = 0; d < 256; ++d) partial += embS[q * 256 + d] * wp[(size_t)d * L];
    }
    red[q][li] = partial;
    __syncthreads();
    if (t < 64 && l0 + t < L) {
        float o = red[0][t] + red[1][t] + red[2][t] + red[3][t] + bias[l0 + t];
        ws[O_OFF + b * L + l0 + t] = o;
    }
}

// K1b: per-batch scalar params + zero atomics. grid(B), 128 thr.
__global__ __launch_bounds__(128) void k1b_act(float* __restrict__ ws) {
    const int b = blockIdx.x;
    const int t = threadIdx.x;                 // 128 threads = 2 waves
    const float* o = ws + O_OFF + b * L;
    float kv = o[t];
    float sq = kv * kv;
    #pragma unroll
    for (int off = 32; off >= 1; off >>= 1) sq += __shfl_xor(sq, off, 64);
    __shared__ float s01[2];
    if ((t & 63) == 0) s01[t >> 6] = sq;
    __syncthreads();
    if (t == 0) {
        float knorm = sqrtf(s01[0] + s01[1]);
        float beta  = softplusf(o[M]);
        float g     = sigmoidf(o[M + 1]);
        float x0 = o[M + 2], x1 = o[M + 3], x2 = o[M + 4];
        float mx = fmaxf(x0, fmaxf(x1, x2));
        float e0 = expf(x0 - mx), e1 = expf(x1 - mx), e2 = expf(x2 - mx);
        float inv = 1.f / (e0 + e1 + e2);
        float gamma = 1.f + softplusf(o[M + 5]);
        float* p = ws + P_OFF + b * 8;
        p[0] = beta; p[1] = g; p[2] = e0 * inv; p[3] = e1 * inv; p[4] = e2 * inv;
        p[5] = gamma; p[6] = knorm;
        ws[S1_OFF + b] = 0.f;
        ws[S2_OFF + b] = 0.f;
    }
}

// K2: z[b,n] = beta*cos_sim(mem[b,n,:],k); atomic S1 += sum exp(z).
// 16 lanes per row (8 floats/lane), 4 rows per wave-iteration -> 2 shuffles/row.
// grid(N/64, B), 256 thr = 4 waves, 16 rows/wave.
__global__ __launch_bounds__(256) void k2_sim(const float* __restrict__ mem,
                                              float* __restrict__ ws) {
    const int b    = blockIdx.y;
    const int n0   = blockIdx.x * 64;
    const int t    = threadIdx.x;
    const int wave = t >> 6, lane = t & 63;
    __shared__ float kS[M];
    if (t < M) kS[t] = ws[O_OFF + b * L + t];
    __syncthreads();
    const float beta  = ws[P_OFF + b * 8 + 0];
    const float knorm = ws[P_OFF + b * 8 + 6];
    float* z = ws + Z_OFF + (size_t)b * N;
    const int seg = (lane & 15) * 8;           // this lane's 8-elem segment of M
    const float4 ka = *(const float4*)&kS[seg];
    const float4 kb = *(const float4*)&kS[seg + 4];
    float lsum = 0.f;
    #pragma unroll
    for (int it = 0; it < 4; ++it) {
        const int n = n0 + wave * 16 + it * 4 + (lane >> 4);
        const float* mp = mem + ((size_t)b * N + n) * M + seg;
        const float4 ma = *(const float4*)mp;
        const float4 mb = *(const float4*)(mp + 4);
        float dot = ma.x*ka.x + ma.y*ka.y + ma.z*ka.z + ma.w*ka.w
                  + mb.x*kb.x + mb.y*kb.y + mb.z*kb.z + mb.w*kb.w;
        float sq  = ma.x*ma.x + ma.y*ma.y + ma.z*ma.z + ma.w*ma.w
                  + mb.x*mb.x + mb.y*mb.y + mb.z*mb.z + mb.w*mb.w;
        #pragma unroll
        for (int off = 1; off <= 8; off <<= 1) {   // reduce within 16-lane group
            dot += __shfl_xor(dot, off, 64);
            sq  += __shfl_xor(sq,  off, 64);
        }
        if ((lane & 15) == 0) {
            const float sim = dot / (sqrtf(sq) * knorm + EPSF);
            const float zz  = beta * sim;
            z[n] = zz;
            lsum += expf(zz);
        }
    }
    lsum += __shfl_xor(lsum, 16, 64);          // gather leaders 0,16,32,48
    lsum += __shfl_xor(lsum, 32, 64);
    __shared__ float acc[4];
    if (lane == 0) acc[wave] = lsum;
    __syncthreads();
    if (t == 0) atomicAdd(ws + S1_OFF + b, acc[0] + acc[1] + acc[2] + acc[3]);
}

// K3: w_sh[b,n] = (s0*wg(n-1)+s1*wg(n)+s2*wg(n+1))^gamma, stash into out's w
// region; atomic S2 += sum.  grid(N/256, B).
__global__ __launch_bounds__(256) void k3_shsum(const float* __restrict__ w_prev,
                                                float* __restrict__ ws,
                                                float* __restrict__ out) {
    const int b = blockIdx.y;
    const int n = blockIdx.x * 256 + threadIdx.x;
    const float* p = ws + P_OFF + b * 8;
    const float g = p[1], s0 = p[2], s1 = p[3], s2 = p[4], gamma = p[5];
    const float invS1 = 1.f / ws[S1_OFF + b];
    const float* z  = ws + Z_OFF + (size_t)b * N;
    const float* wp = w_prev + (size_t)b * N;
    const int nm = (n == 0)     ? N - 1 : n - 1;
    const int np = (n == N - 1) ? 0     : n + 1;
    const float gm1 = 1.f - g;
    const float wgm = g * expf(z[nm]) * invS1 + gm1 * wp[nm];
    const float wg0 = g * expf(z[n ]) * invS1 + gm1 * wp[n ];
    const float wgp = g * expf(z[np]) * invS1 + gm1 * wp[np];
    const float wt  = s0 * wgm + s1 * wg0 + s2 * wgp;
    const float v = powf(wt, gamma);
    out[(size_t)b * N + n] = v;                // stash w_sh; k4 scales by invS2
    float r = v;
    #pragma unroll
    for (int off = 32; off >= 1; off >>= 1) r += __shfl_xor(r, off, 64);
    __shared__ float acc[4];
    if ((threadIdx.x & 63) == 0) acc[threadIdx.x >> 6] = r;
    __syncthreads();
    if (threadIdx.x == 0) atomicAdd(ws + S2_OFF + b, acc[0] + acc[1] + acc[2] + acc[3]);
}

// K4: wv = w_sh[n]*invS2 (finalize w in place); new_mem = mem*(1-wv*e)+wv*a.
// Pure streaming: 32 lanes per row, float4/lane, 2 rows per wave-iteration.
// grid(N/64, B), 256 thr = 4 waves, 16 rows/wave.
__global__ __launch_bounds__(256) void k4_write(const float* __restrict__ mem,
                                                const float* __restrict__ ws,
                                                float* __restrict__ out) {
    const int b    = blockIdx.y;
    const int n0   = blockIdx.x * 64;
    const int t    = threadIdx.x;
    const int wave = t >> 6, lane = t & 63;
    __shared__ float eS[M], aS[M];
    if (t < M) {
        eS[t] = sigmoidf(ws[O_OFF + b * L + M + 6 + t]);
        aS[t] = ws[O_OFF + b * L + 2 * M + 6 + t];
    }
    __syncthreads();
    const float invS2 = 1.f / (ws[S2_OFF + b] + EPSF);
    float* w_out = out + (size_t)b * N;
    float* m_out = out + (size_t)B * N;
    const int col = (lane & 31) * 4;
    const float4 ev = *(const float4*)&eS[col];
    const float4 av = *(const float4*)&aS[col];
    #pragma unroll
    for (int it = 0; it < 8; ++it) {
        const int n = n0 + wave * 16 + it * 2 + (lane >> 5);
        const float wsh = w_out[n];            // w_sh stashed by k3 (read < write)
        const float wv  = wsh * invS2;
        const size_t idx = ((size_t)b * N + n) * M + col;
        const float4 mv = *(const float4*)(mem + idx);
        float4 r;
        r.x = fmaf(mv.x, fmaf(-wv, ev.x, 1.f), wv * av.x);
        r.y = fmaf(mv.y, fmaf(-wv, ev.y, 1.f), wv * av.y);
        r.z = fmaf(mv.z, fmaf(-wv, ev.z, 1.f), wv * av.z);
        r.w = fmaf(mv.w, fmaf(-wv, ev.w, 1.f), wv * av.w);
        *(float4*)(m_out + idx) = r;
        if ((lane & 31) == 0) w_out[n] = wv;   // finalize w
    }
}

extern "C" void kernel_launch(void* const* d_in, const int* in_sizes, int n_in,
                              void* d_out, int out_size, void* d_ws, size_t ws_size,
                              hipStream_t stream) {
    const float* emb    = (const float*)d_in[0];
    const float* w_prev = (const float*)d_in[1];
    const float* mem    = (const float*)d_in[2];
    const float* W      = (const float*)d_in[3];
    const float* bias   = (const float*)d_in[4];
    float* ws  = (float*)d_ws;    // needs (B*L + B*8 + 2*B + B*N)*4 ≈ 2.15 MB
    float* out = (float*)d_out;

    k1_gemm <<<dim3(7, B),      256, 0, stream>>>(emb, W, bias, ws);
    k1b_act <<<dim3(B),         128, 0, stream>>>(ws);
    k2_sim  <<<dim3(N / 64, B), 256, 0, stream>>>(mem, ws);
    k3_shsum<<<dim3(N / 256, B),256, 0, stream>>>(w_prev, ws, out);
    k4_write<<<dim3(N / 64, B), 256, 0, stream>>>(mem, ws, out);
}